// Round 9
// baseline (395.749 us; speedup 1.0000x reference)
//
#include <hip/hip_runtime.h>

// ---------------------------------------------------------------------------
// GraphSAGE 2-layer hetero (R=2) + edge dot scorer.  Round 9:
//  * Layer 1 aggregate-first: agg1x gathers BOTH relations from the single
//    12.8 MB xb table (halves per-XCD unique-line footprint vs y0/y1) and
//    writes bf16 means m0,m1. gemm3 (MFMA, K=384) fuses
//    relu(xb@Wc1 + m0@Wn1a + m1@Wn1b + bc1) with ONE accumulator -> no f32
//    z1 round-trip at all.
//  * Layer 2 transform-first kept (64-col gather rows) but gemm2 computes
//    z2(bf16!)/t0/t1 in one pass over A (one A read, 12 MFMA/kstep).
//  * score: single merged kernel for pos+neg.
//  * bucket CSR build unchanged (round 6/8).
// ---------------------------------------------------------------------------

#define BW 128            // nodes per radix bucket (pow2)
#define NBK_MAX 1024
#define EPB 8192          // edges per block in radix passes

typedef __attribute__((ext_vector_type(8))) short bf16x8;
typedef __attribute__((ext_vector_type(4))) float floatx4;

__device__ __forceinline__ unsigned short f2bf(float f) {
    unsigned u = __float_as_uint(f);
    unsigned r = u + 0x7FFFu + ((u >> 16) & 1u);
    return (unsigned short)(r >> 16);
}
__device__ __forceinline__ unsigned pack2(float a, float b) {
    return (unsigned)f2bf(a) | ((unsigned)f2bf(b) << 16);
}
__device__ __forceinline__ float bflo(unsigned v) { return __uint_as_float(v << 16); }
__device__ __forceinline__ float bfhi(unsigned v) { return __uint_as_float(v & 0xFFFF0000u); }

// ---- radix pass A: per-(r,bucket) counts --------------------------------
__global__ __launch_bounds__(256) void
bucket_count_kernel(const int* __restrict__ edges, int* __restrict__ bcnt,
                    int NBK, int E)
{
    __shared__ int cnt[2 * NBK_MAX];
    const int rbT = 2 * NBK;
    const int t = threadIdx.x;
    for (int k = t; k < rbT; k += 256) cnt[k] = 0;
    __syncthreads();
    long long start = (long long)blockIdx.x * EPB;
    long long twoE = 2LL * E;
    for (int u = 0; u < EPB / 256; ++u) {
        long long idx = start + u * 256 + t;
        if (idx < twoE) {
            int r = idx >= E;
            int e = (int)(idx - (long long)r * E);
            int d = edges[(size_t)r * 2 * E + E + e];
            atomicAdd(&cnt[r * NBK + (d >> 7)], 1);
        }
    }
    __syncthreads();
    for (int k = t; k < rbT; k += 256)
        if (cnt[k]) atomicAdd(&bcnt[k], cnt[k]);
}

// ---- radix pass B: exclusive scan of bucket counts ----------------------
__global__ __launch_bounds__(1024) void
bucket_scan_kernel(const int* __restrict__ bcnt, int* __restrict__ bko,
                   int rbT, int twoE)
{
    __shared__ int sm[1024];
    int t = threadIdx.x;
    int v = (t < rbT) ? bcnt[t] : 0;
    sm[t] = v;
    __syncthreads();
    for (int s = 1; s < 1024; s <<= 1) {
        int u = (t >= s) ? sm[t - s] : 0;
        __syncthreads();
        sm[t] += u;
        __syncthreads();
    }
    if (t < rbT) bko[t] = sm[t] - v;
    if (t == 0) bko[rbT] = twoE;
}

// ---- radix pass C: partition into bucket-grouped (src,dst) pairs --------
__global__ __launch_bounds__(256) void
partition_kernel(const int* __restrict__ edges, const int* __restrict__ bko,
                 int* __restrict__ gcur, uint2* __restrict__ staging,
                 int NBK, int E)
{
    __shared__ int cnt[2 * NBK_MAX];
    __shared__ int base[2 * NBK_MAX];
    const int rbT = 2 * NBK;
    const int t = threadIdx.x;
    for (int k = t; k < rbT; k += 256) cnt[k] = 0;
    __syncthreads();
    long long start = (long long)blockIdx.x * EPB;
    long long twoE = 2LL * E;
    for (int u = 0; u < EPB / 256; ++u) {
        long long idx = start + u * 256 + t;
        if (idx < twoE) {
            int r = idx >= E;
            int e = (int)(idx - (long long)r * E);
            int d = edges[(size_t)r * 2 * E + E + e];
            atomicAdd(&cnt[r * NBK + (d >> 7)], 1);
        }
    }
    __syncthreads();
    for (int k = t; k < rbT; k += 256) {
        int c0 = cnt[k];
        if (c0) base[k] = bko[k] + atomicAdd(&gcur[k], c0);
        cnt[k] = 0;
    }
    __syncthreads();
    for (int u = 0; u < EPB / 256; ++u) {
        long long idx = start + u * 256 + t;
        if (idx < twoE) {
            int r = idx >= E;
            int e = (int)(idx - (long long)r * E);
            int s = edges[(size_t)r * 2 * E + e];
            int d = edges[(size_t)r * 2 * E + E + e];
            int rb = r * NBK + (d >> 7);
            int pos = atomicAdd(&cnt[rb], 1);
            staging[(size_t)base[rb] + pos] = make_uint2((unsigned)s, (unsigned)d);
        }
    }
}

// ---- radix pass D: per-bucket node hist/scan -> off[] and csr[] ----------
__global__ __launch_bounds__(256) void
bucket_csr_kernel(const uint2* __restrict__ staging, const int* __restrict__ bko,
                  int* __restrict__ csr, int* __restrict__ off,
                  int NBK, int N)
{
    __shared__ int hist[BW], excl[BW], cur[BW], sc[BW];
    const int rb = blockIdx.x;
    const int r = rb / NBK;
    const int b = rb % NBK;
    const int node0 = b * BW;
    const int nn = min(BW, N - node0);
    const int cbase = bko[rb];
    const int c = bko[rb + 1] - cbase;
    const int t = threadIdx.x;

    if (t < BW) { hist[t] = 0; cur[t] = 0; }
    __syncthreads();
    for (int k = t; k < c; k += 256)
        atomicAdd(&hist[(int)staging[(size_t)cbase + k].y - node0], 1);
    __syncthreads();
    if (t < BW) sc[t] = hist[t];
    __syncthreads();
    for (int s = 1; s < BW; s <<= 1) {
        int v = (t < BW && t >= s) ? sc[t - s] : 0;
        __syncthreads();
        if (t < BW) sc[t] += v;
        __syncthreads();
    }
    if (t < BW) excl[t] = sc[t] - hist[t];
    if (t < nn) off[(size_t)r * N + node0 + t] = cbase + excl[t];
    __syncthreads();
    for (int k = t; k < c; k += 256) {
        uint2 pr = staging[(size_t)cbase + k];
        int l = (int)pr.y - node0;
        int pos = atomicAdd(&cur[l], 1);
        csr[(size_t)cbase + excl[l] + pos] = (int)pr.x;
    }
}

// ---- f32 -> bf16 --------------------------------------------------------
__global__ void cvt_kernel(const float* __restrict__ in,
                           unsigned short* __restrict__ o, int n4)
{
    int t = blockIdx.x * blockDim.x + threadIdx.x;
    if (t >= n4) return;
    float4 v = ((const float4*)in)[t];
    ushort4 r;
    r.x = f2bf(v.x); r.y = f2bf(v.y); r.z = f2bf(v.z); r.w = f2bf(v.w);
    ((ushort4*)o)[t] = r;
}

// ---- weight prep: combined-Wself / Wn -> bf16 W^T rows, biases ----------
__global__ void prep_kernel(const float* __restrict__ Ws1, const float* __restrict__ Wn1,
                            const float* __restrict__ b1,
                            const float* __restrict__ Ws2, const float* __restrict__ Wn2,
                            const float* __restrict__ b2,
                            unsigned short* __restrict__ WT1z, unsigned short* __restrict__ WT1a,
                            unsigned short* __restrict__ WT1b, float* __restrict__ bc1,
                            unsigned short* __restrict__ WT2z, unsigned short* __restrict__ WT2a,
                            unsigned short* __restrict__ WT2b, float* __restrict__ bc2)
{
    int t = blockIdx.x * blockDim.x + threadIdx.x;
    if (t < 16384) {                 // layer 1: [n][k] <- [k][n], n,k < 128
        int n = t >> 7, k = t & 127;
        int in = k * 128 + n;
        WT1z[t] = f2bf(Ws1[in] + Ws1[16384 + in]);
        WT1a[t] = f2bf(Wn1[in]);
        WT1b[t] = f2bf(Wn1[16384 + in]);
    }
    if (t < 8192) {                  // layer 2: n < 64, k < 128
        int n = t >> 7, k = t & 127;
        int in = k * 64 + n;
        WT2z[t] = f2bf(Ws2[in] + Ws2[8192 + in]);
        WT2a[t] = f2bf(Wn2[in]);
        WT2b[t] = f2bf(Wn2[8192 + in]);
    }
    if (t < 128) bc1[t] = b1[t] + b1[128 + t];
    if (t < 64)  bc2[t] = b2[t] + b2[64 + t];
}

// ---- agg1x: wave per node, gather xb rows for BOTH relations ------------
// m0 = mean_r0(xb), m1 = mean_r1(xb)  -> bf16 [N,128] each
__global__ __launch_bounds__(256) void
agg1x_kernel(const unsigned short* __restrict__ xb,
             const int* __restrict__ csr, const int* __restrict__ off,
             unsigned short* __restrict__ m0, unsigned short* __restrict__ m1,
             int N, int twoE)
{
    int w = blockIdx.x * 4 + (threadIdx.x >> 6);
    int lane = threadIdx.x & 63;
    if (w >= N) return;
    const int col = lane * 2;

    float sx0 = 0.f, sy0 = 0.f, sx1 = 0.f, sy1 = 0.f;
    int o0 = off[w], o1 = off[w + 1];
    int d0 = o1 - o0;
    int j = o0;
    for (; j + 7 < o1; j += 8) {
        int s0 = csr[j], s1 = csr[j + 1], s2 = csr[j + 2], s3 = csr[j + 3];
        int s4 = csr[j + 4], s5 = csr[j + 5], s6 = csr[j + 6], s7 = csr[j + 7];
        unsigned a0 = *(const unsigned*)(xb + (size_t)s0 * 128 + col);
        unsigned a1 = *(const unsigned*)(xb + (size_t)s1 * 128 + col);
        unsigned a2 = *(const unsigned*)(xb + (size_t)s2 * 128 + col);
        unsigned a3 = *(const unsigned*)(xb + (size_t)s3 * 128 + col);
        unsigned a4 = *(const unsigned*)(xb + (size_t)s4 * 128 + col);
        unsigned a5 = *(const unsigned*)(xb + (size_t)s5 * 128 + col);
        unsigned a6 = *(const unsigned*)(xb + (size_t)s6 * 128 + col);
        unsigned a7 = *(const unsigned*)(xb + (size_t)s7 * 128 + col);
        sx0 += ((bflo(a0) + bflo(a1)) + (bflo(a2) + bflo(a3))) +
               ((bflo(a4) + bflo(a5)) + (bflo(a6) + bflo(a7)));
        sy0 += ((bfhi(a0) + bfhi(a1)) + (bfhi(a2) + bfhi(a3))) +
               ((bfhi(a4) + bfhi(a5)) + (bfhi(a6) + bfhi(a7)));
    }
    for (; j < o1; ++j) {
        unsigned a = *(const unsigned*)(xb + (size_t)csr[j] * 128 + col);
        sx0 += bflo(a); sy0 += bfhi(a);
    }
    int p = N + w;
    o0 = off[p];
    o1 = (p + 1 < 2 * N) ? off[p + 1] : twoE;
    int d1 = o1 - o0;
    j = o0;
    for (; j + 7 < o1; j += 8) {
        int s0 = csr[j], s1 = csr[j + 1], s2 = csr[j + 2], s3 = csr[j + 3];
        int s4 = csr[j + 4], s5 = csr[j + 5], s6 = csr[j + 6], s7 = csr[j + 7];
        unsigned a0 = *(const unsigned*)(xb + (size_t)s0 * 128 + col);
        unsigned a1 = *(const unsigned*)(xb + (size_t)s1 * 128 + col);
        unsigned a2 = *(const unsigned*)(xb + (size_t)s2 * 128 + col);
        unsigned a3 = *(const unsigned*)(xb + (size_t)s3 * 128 + col);
        unsigned a4 = *(const unsigned*)(xb + (size_t)s4 * 128 + col);
        unsigned a5 = *(const unsigned*)(xb + (size_t)s5 * 128 + col);
        unsigned a6 = *(const unsigned*)(xb + (size_t)s6 * 128 + col);
        unsigned a7 = *(const unsigned*)(xb + (size_t)s7 * 128 + col);
        sx1 += ((bflo(a0) + bflo(a1)) + (bflo(a2) + bflo(a3))) +
               ((bflo(a4) + bflo(a5)) + (bflo(a6) + bflo(a7)));
        sy1 += ((bfhi(a0) + bfhi(a1)) + (bfhi(a2) + bfhi(a3))) +
               ((bfhi(a4) + bfhi(a5)) + (bfhi(a6) + bfhi(a7)));
    }
    for (; j < o1; ++j) {
        unsigned a = *(const unsigned*)(xb + (size_t)csr[j] * 128 + col);
        sx1 += bflo(a); sy1 += bfhi(a);
    }
    float inv0 = 1.0f / fmaxf((float)d0, 1.0f);
    float inv1 = 1.0f / fmaxf((float)d1, 1.0f);
    *(unsigned*)(m0 + (size_t)w * 128 + col) = pack2(sx0 * inv0, sy0 * inv0);
    *(unsigned*)(m1 + (size_t)w * 128 + col) = pack2(sx1 * inv1, sy1 * inv1);
}

// ---- gemm3 (layer 1): h1 = relu(xb@W0 + m0@W1 + m1@W2 + bias) -> bf16 ---
// All A [N,128] bf16; WT* [128,128] bf16 W^T rows. One accumulator, K=384.
__global__ __launch_bounds__(256) void
gemm3_mfma_kernel(const unsigned short* __restrict__ xb,
                  const unsigned short* __restrict__ m0,
                  const unsigned short* __restrict__ m1,
                  const unsigned short* __restrict__ WT0,
                  const unsigned short* __restrict__ WT1,
                  const unsigned short* __restrict__ WT2,
                  const float* __restrict__ bias,
                  unsigned short* __restrict__ h1b, int N)
{
    __shared__ float eb[64][129];
    const int tid = threadIdx.x;
    const int wave = tid >> 6;
    const int lane = tid & 63;
    const int m = lane & 15;
    const int quad = lane >> 4;

    floatx4 acc[8];
    const floatx4 z4 = {0.f, 0.f, 0.f, 0.f};
#pragma unroll
    for (int t = 0; t < 8; ++t) acc[t] = z4;

    int arow = blockIdx.x * 64 + wave * 16 + m;
    if (arow >= N) arow = N - 1;

    const unsigned short* Asrc[3] = {xb, m0, m1};
    const unsigned short* Bsrc[3] = {WT0, WT1, WT2};
#pragma unroll
    for (int s3 = 0; s3 < 3; ++s3) {
        const unsigned short* ap = Asrc[s3] + (size_t)arow * 128 + quad * 8;
        const unsigned short* bp = Bsrc[s3];
#pragma unroll
        for (int s = 0; s < 4; ++s) {
            bf16x8 a = *(const bf16x8*)(ap + s * 32);
#pragma unroll
            for (int t = 0; t < 8; ++t) {
                bf16x8 b = *(const bf16x8*)(bp + (size_t)(t * 16 + m) * 128 + s * 32 + quad * 8);
                acc[t] = __builtin_amdgcn_mfma_f32_16x16x32_bf16(a, b, acc[t], 0, 0, 0);
            }
        }
    }

#pragma unroll
    for (int t = 0; t < 8; ++t)
#pragma unroll
        for (int i = 0; i < 4; ++i)
            eb[wave * 16 + quad * 4 + i][t * 16 + m] = acc[t][i];
    __syncthreads();

#pragma unroll
    for (int j = 0; j < 4; ++j) {
        int lr = wave * 16 + j * 4 + quad;
        int grow = blockIdx.x * 64 + lr;
        if (grow < N) {
#pragma unroll
            for (int i = 0; i < 2; ++i) {
                int c0 = (i * 16 + m) * 4;
                float v0 = fmaxf(eb[lr][c0 + 0] + bias[c0 + 0], 0.0f);
                float v1 = fmaxf(eb[lr][c0 + 1] + bias[c0 + 1], 0.0f);
                float v2 = fmaxf(eb[lr][c0 + 2] + bias[c0 + 2], 0.0f);
                float v3 = fmaxf(eb[lr][c0 + 3] + bias[c0 + 3], 0.0f);
                ushort4 u;
                u.x = f2bf(v0); u.y = f2bf(v1); u.z = f2bf(v2); u.w = f2bf(v3);
                *(ushort4*)(h1b + (size_t)grow * 128 + c0) = u;
            }
        }
    }
}

// ---- gemm2 (layer 2): one A pass -> z2(bf16,+bias), t0, t1 [N,64] -------
__global__ __launch_bounds__(256) void
gemm2_mfma_kernel(const unsigned short* __restrict__ h1b,
                  const unsigned short* __restrict__ WTz,
                  const unsigned short* __restrict__ WTa,
                  const unsigned short* __restrict__ WTb,
                  const float* __restrict__ bias,
                  unsigned short* __restrict__ z2b,
                  unsigned short* __restrict__ t0, unsigned short* __restrict__ t1,
                  int N)
{
    __shared__ float eb[64][65];
    const int tid = threadIdx.x;
    const int wave = tid >> 6;
    const int lane = tid & 63;
    const int m = lane & 15;
    const int quad = lane >> 4;

    floatx4 acc[3][4];
    const floatx4 z4 = {0.f, 0.f, 0.f, 0.f};
#pragma unroll
    for (int o = 0; o < 3; ++o)
#pragma unroll
        for (int t = 0; t < 4; ++t) acc[o][t] = z4;

    int arow = blockIdx.x * 64 + wave * 16 + m;
    if (arow >= N) arow = N - 1;
    const unsigned short* ap = h1b + (size_t)arow * 128 + quad * 8;
    const unsigned short* Bsrc[3] = {WTz, WTa, WTb};

#pragma unroll
    for (int s = 0; s < 4; ++s) {
        bf16x8 a = *(const bf16x8*)(ap + s * 32);
#pragma unroll
        for (int o = 0; o < 3; ++o)
#pragma unroll
            for (int t = 0; t < 4; ++t) {
                bf16x8 b = *(const bf16x8*)(Bsrc[o] + (size_t)(t * 16 + m) * 128 + s * 32 + quad * 8);
                acc[o][t] = __builtin_amdgcn_mfma_f32_16x16x32_bf16(a, b, acc[o][t], 0, 0, 0);
            }
    }

    unsigned short* Od[3] = {z2b, t0, t1};
#pragma unroll
    for (int o = 0; o < 3; ++o) {
#pragma unroll
        for (int t = 0; t < 4; ++t)
#pragma unroll
            for (int i = 0; i < 4; ++i)
                eb[wave * 16 + quad * 4 + i][t * 16 + m] = acc[o][t][i];
        __syncthreads();
#pragma unroll
        for (int j = 0; j < 4; ++j) {
            int lr = wave * 16 + j * 4 + quad;
            int grow = blockIdx.x * 64 + lr;
            if (grow < N) {
                int c0 = m * 4;
                float v0 = eb[lr][c0 + 0], v1 = eb[lr][c0 + 1];
                float v2 = eb[lr][c0 + 2], v3 = eb[lr][c0 + 3];
                if (o == 0) {
                    v0 += bias[c0 + 0]; v1 += bias[c0 + 1];
                    v2 += bias[c0 + 2]; v3 += bias[c0 + 3];
                }
                ushort4 u;
                u.x = f2bf(v0); u.y = f2bf(v1); u.z = f2bf(v2); u.w = f2bf(v3);
                *(ushort4*)(Od[o] + (size_t)grow * 64 + c0) = u;
            }
        }
        __syncthreads();
    }
}

// ---- agg L2: wave per node, 64 cols, 2 edges/iter, unroll x4 -------------
__global__ __launch_bounds__(256) void
agg2_kernel(const unsigned short* __restrict__ t0,
            const unsigned short* __restrict__ t1,
            const unsigned short* __restrict__ z2b,
            const int* __restrict__ csr, const int* __restrict__ off,
            unsigned short* __restrict__ h2b, int N, int twoE)
{
    int w = blockIdx.x * 4 + (threadIdx.x >> 6);
    int lane = threadIdx.x & 63;
    if (w >= N) return;
    const int half = lane >> 5;
    const int col = (lane & 31) * 2;

    float sx0 = 0.f, sy0 = 0.f, sx1 = 0.f, sy1 = 0.f;
    int o0 = off[w], o1 = off[w + 1];
    int d0 = o1 - o0;
    int j = o0 + half;
    for (; j + 6 < o1; j += 8) {
        int s0 = csr[j], s1 = csr[j + 2], s2 = csr[j + 4], s3 = csr[j + 6];
        unsigned a0 = *(const unsigned*)(t0 + (size_t)s0 * 64 + col);
        unsigned a1 = *(const unsigned*)(t0 + (size_t)s1 * 64 + col);
        unsigned a2 = *(const unsigned*)(t0 + (size_t)s2 * 64 + col);
        unsigned a3 = *(const unsigned*)(t0 + (size_t)s3 * 64 + col);
        sx0 += (bflo(a0) + bflo(a1)) + (bflo(a2) + bflo(a3));
        sy0 += (bfhi(a0) + bfhi(a1)) + (bfhi(a2) + bfhi(a3));
    }
    for (; j < o1; j += 2) {
        unsigned a = *(const unsigned*)(t0 + (size_t)csr[j] * 64 + col);
        sx0 += bflo(a); sy0 += bfhi(a);
    }
    int p = N + w;
    o0 = off[p];
    o1 = (p + 1 < 2 * N) ? off[p + 1] : twoE;
    int d1 = o1 - o0;
    j = o0 + half;
    for (; j + 6 < o1; j += 8) {
        int s0 = csr[j], s1 = csr[j + 2], s2 = csr[j + 4], s3 = csr[j + 6];
        unsigned a0 = *(const unsigned*)(t1 + (size_t)s0 * 64 + col);
        unsigned a1 = *(const unsigned*)(t1 + (size_t)s1 * 64 + col);
        unsigned a2 = *(const unsigned*)(t1 + (size_t)s2 * 64 + col);
        unsigned a3 = *(const unsigned*)(t1 + (size_t)s3 * 64 + col);
        sx1 += (bflo(a0) + bflo(a1)) + (bflo(a2) + bflo(a3));
        sy1 += (bfhi(a0) + bfhi(a1)) + (bfhi(a2) + bfhi(a3));
    }
    for (; j < o1; j += 2) {
        unsigned a = *(const unsigned*)(t1 + (size_t)csr[j] * 64 + col);
        sx1 += bflo(a); sy1 += bfhi(a);
    }
    sx0 += __shfl_xor(sx0, 32);
    sy0 += __shfl_xor(sy0, 32);
    sx1 += __shfl_xor(sx1, 32);
    sy1 += __shfl_xor(sy1, 32);
    if (half == 0) {
        float inv0 = 1.0f / fmaxf((float)d0, 1.0f);
        float inv1 = 1.0f / fmaxf((float)d1, 1.0f);
        unsigned zz = *(const unsigned*)(z2b + (size_t)w * 64 + col);
        float hx = bflo(zz) + sx0 * inv0 + sx1 * inv1;
        float hy = bfhi(zz) + sy0 * inv0 + sy1 * inv1;
        *(unsigned*)(h2b + (size_t)w * 64 + col) = pack2(hx, hy);
    }
}

// ---- merged score: pos then neg; 8 lanes/edge ---------------------------
__global__ __launch_bounds__(256) void
score_all_kernel(const unsigned short* __restrict__ h, // [N,64] bf16
                 const int* __restrict__ psrc, const int* __restrict__ pdst,
                 const int* __restrict__ nsrc, const int* __restrict__ ndst,
                 float* __restrict__ out, int E, int En)
{
    int t = blockIdx.x * blockDim.x + threadIdx.x;
    int e = t >> 3;
    int c = t & 7;
    if (e >= E + En) return;
    int si, di;
    if (e < E) { si = psrc[e]; di = pdst[e]; }
    else       { si = nsrc[e - E]; di = ndst[e - E]; }
    uint4 va = *(const uint4*)(h + (size_t)si * 64 + c * 8);
    uint4 vb = *(const uint4*)(h + (size_t)di * 64 + c * 8);
    float s = 0.0f;
    s = fmaf(bflo(va.x), bflo(vb.x), s);
    s = fmaf(bfhi(va.x), bfhi(vb.x), s);
    s = fmaf(bflo(va.y), bflo(vb.y), s);
    s = fmaf(bfhi(va.y), bfhi(vb.y), s);
    s = fmaf(bflo(va.z), bflo(vb.z), s);
    s = fmaf(bfhi(va.z), bfhi(vb.z), s);
    s = fmaf(bflo(va.w), bflo(vb.w), s);
    s = fmaf(bfhi(va.w), bfhi(vb.w), s);
    s += __shfl_xor(s, 1);
    s += __shfl_xor(s, 2);
    s += __shfl_xor(s, 4);
    if (c == 0) out[e] = s;
}

extern "C" void kernel_launch(void* const* d_in, const int* in_sizes, int n_in,
                              void* d_out, int out_size, void* d_ws, size_t ws_size,
                              hipStream_t stream)
{
    const float* x     = (const float*)d_in[0];
    const int*   edges = (const int*)d_in[1];
    const int*   neg   = (const int*)d_in[2];
    const float* Wn1   = (const float*)d_in[3];
    const float* Ws1   = (const float*)d_in[4];
    const float* b1    = (const float*)d_in[5];
    const float* Wn2   = (const float*)d_in[6];
    const float* Ws2   = (const float*)d_in[7];
    const float* b2    = (const float*)d_in[8];
    float* out = (float*)d_out;

    const int Fin = 128, R = 2;
    const int N  = in_sizes[0] / Fin;        // 50000
    const int E  = in_sizes[1] / (R * 2);    // 800000
    const int En = in_sizes[2] / 2;          // 800000
    const int twoE = 2 * E;
    const int NBK = (N + BW - 1) / BW;       // 391
    const int rbT = 2 * NBK;

    // ---- workspace layout ----
    unsigned short* xb  = (unsigned short*)d_ws;       // [N,128] bf16
    unsigned short* h1b = xb + (size_t)N * 128;        // [N,128] bf16
    unsigned short* m0  = h1b + (size_t)N * 128;       // [N,128] bf16
    unsigned short* m1  = m0 + (size_t)N * 128;        // [N,128] bf16
    uint2* staging = (uint2*)(m1 + (size_t)N * 128);   // [2E] pairs
    unsigned short* WT1z = (unsigned short*)(staging + (size_t)twoE); // [128,128]
    unsigned short* WT1a = WT1z + 16384;
    unsigned short* WT1b = WT1a + 16384;
    unsigned short* WT2z = WT1b + 16384;               // [64,128]
    unsigned short* WT2a = WT2z + 8192;
    unsigned short* WT2b = WT2a + 8192;
    float* bc1 = (float*)(WT2b + 8192);                // [128]
    float* bc2 = bc1 + 128;                            // [64]
    int* bcnt = (int*)(bc2 + 64);                      // [2*NBK_MAX]
    int* gcur = bcnt + 2 * NBK_MAX;                    // [2*NBK_MAX]
    int* bko  = gcur + 2 * NBK_MAX;                    // [2*NBK_MAX+1]
    int* off  = bko + 2 * NBK_MAX + 1;                 // [2N]
    int* csr  = off + (size_t)2 * N;                   // [2E]

    // layer-2 aliases (m0/m1 are dead after gemm3)
    unsigned short* z2b = m0;                          // [N,64]
    unsigned short* t0  = m0 + (size_t)N * 64;         // [N,64]
    unsigned short* t1  = m1;                          // [N,64]
    unsigned short* h2b = m1 + (size_t)N * 64;         // [N,64]

    const int BS = 256;
    const int edge_blocks = (twoE + EPB - 1) / EPB;
    const int gx = (N + 63) / 64;

    // ---- CSR build (radix by dst bucket) ----
    hipMemsetAsync(bcnt, 0, (size_t)4 * NBK_MAX * sizeof(int), stream);
    bucket_count_kernel<<<edge_blocks, BS, 0, stream>>>(edges, bcnt, NBK, E);
    bucket_scan_kernel<<<1, 1024, 0, stream>>>(bcnt, bko, rbT, twoE);
    partition_kernel<<<edge_blocks, BS, 0, stream>>>(edges, bko, gcur, staging, NBK, E);
    bucket_csr_kernel<<<rbT, BS, 0, stream>>>(staging, bko, csr, off, NBK, N);

    // ---- prep ----
    cvt_kernel<<<(N * 32 + BS - 1) / BS, BS, 0, stream>>>(x, xb, N * 32);
    prep_kernel<<<(16384 + BS - 1) / BS, BS, 0, stream>>>(
        Ws1, Wn1, b1, Ws2, Wn2, b2,
        WT1z, WT1a, WT1b, bc1, WT2z, WT2a, WT2b, bc2);

    // ---- Layer 1: aggregate-first (single xb table), fused MFMA GEMM ----
    agg1x_kernel<<<(N + 3) / 4, BS, 0, stream>>>(xb, csr, off, m0, m1, N, twoE);
    gemm3_mfma_kernel<<<gx, BS, 0, stream>>>(xb, m0, m1, WT1z, WT1a, WT1b, bc1, h1b, N);

    // ---- Layer 2: transform-first (64-col gather rows), z2 in bf16 ----
    gemm2_mfma_kernel<<<gx, BS, 0, stream>>>(h1b, WT2z, WT2a, WT2b, bc2, z2b, t0, t1, N);
    agg2_kernel<<<(N + 3) / 4, BS, 0, stream>>>(t0, t1, z2b, csr, off, h2b, N, twoE);

    // ---- Scores (merged) ----
    score_all_kernel<<<((E + En) * 8 + BS - 1) / BS, BS, 0, stream>>>(
        h2b, edges, edges + E, neg, neg + En, out, E, En);
}